// Round 3
// baseline (6846.818 us; speedup 1.0000x reference)
//
#include <hip/hip_runtime.h>

// Batched time-varying LQR: Riccati backward pass + forward rollout.
// T=64, B=128, NS=64 (state), NC=32 (control), NSC=96.
// One workgroup (1024 threads = 16 waves) per batch element b; V (symmetric)
// lives in LDS across the 64 sequential timesteps. Forward pass reads K,k
// (as S columns) from d_ws.
//
// R1 -> R3: 256 -> 1024 threads/block. R1 counters: VALUBusy 6.7%,
// Occupancy 5.8% (= 1 wave/SIMD, zero latency hiding). Finer tiles
// (2x3 / 3x3 / 2x2) keep VGPR low so 4 waves/SIMD fit.
// (R2 failed to compile: local `cg` illegally redeclared the parameter `cg`.)

constexpr int T_   = 64;
constexpr int B_   = 128;
constexpr int NS_  = 64;
constexpr int NC_  = 32;
constexpr int NSC_ = 96;

// LDS layout (floats), total 30048 floats = 120,192 B (<160 KiB/CU)
//  Vs  [64][68]   @0      (V, symmetric, padded stride 68)
//  Fs  [64][96]   @4352   (F tile; reused as Bs[64][68] in phase F)
//  Ws  [64][100]  @10496  (W = V F)
//  Qs  [96][100]  @16896  (Q; reused as F^T in forward pass)
//  Ss  [32][68]   @26496  (S = Quu^{-1} [Qux | qu])
//  LT  [32][33]   @28672  (Cholesky factor, transposed: LT[k][i] = L[i][k])
//  invd[32]       @29728
//  qv  [96]       @29760  (q; reused as tau in forward)
//  hv  [64]       @29856  (h = v + V f)
//  vv  [64]       @29920  (v)
//  fv  [64]       @29984  (f)

__global__ __launch_bounds__(1024) void lqr_all(
    const float* __restrict__ Cg, const float* __restrict__ cg,
    const float* __restrict__ Fg, const float* __restrict__ fg,
    const float* __restrict__ x0g, float* __restrict__ outg,
    float* __restrict__ Sws)
{
  const int b   = blockIdx.x;
  const int tid = threadIdx.x;
  const int rw  = tid >> 5;   // 0..31 (wave-row coordinate)
  const int cw  = tid & 31;   // 0..31 (lane-column coordinate)

  __shared__ float smem[30048];
  float (*Vs)[68]   = (float(*)[68]) (smem + 0);
  float (*Fs)[96]   = (float(*)[96]) (smem + 4352);
  float (*Bs)[68]   = (float(*)[68]) (smem + 4352);   // aliases Fs (F dead by then)
  float (*Ws)[100]  = (float(*)[100])(smem + 10496);
  float (*Qs)[100]  = (float(*)[100])(smem + 16896);
  float (*Ss)[68]   = (float(*)[68]) (smem + 26496);
  float (*LT)[33]   = (float(*)[33]) (smem + 28672);
  float* invd = smem + 29728;
  float* qv   = smem + 29760;
  float* hv   = smem + 29856;
  float* vv   = smem + 29920;
  float* fv   = smem + 29984;

  // init V = 0, v = 0
  for (int e = tid; e < 4352; e += 1024) smem[e] = 0.f;
  if (tid < NS_) vv[tid] = 0.f;
  __syncthreads();

  // ================= backward Riccati pass =================
  for (int t = T_ - 1; t >= 0; --t) {
    const size_t tb = (size_t)t * B_ + b;
    const float* Ct = Cg + tb * (NSC_ * NSC_);
    const float* ct = cg + tb * NSC_;
    const float* Ft = Fg + tb * (NS_ * NSC_);
    const float* ft = fg + tb * NS_;

    // ---- phase A: load F (64x96 = 1536 float4), c (96), f (64)
    {
      const float4* F4 = (const float4*)Ft;
      {
        int e4 = tid;                       // 0..1023
        float4 val = F4[e4];
        int r = e4 / 24, c4 = (e4 % 24) * 4;
        *(float4*)&Fs[r][c4] = val;
      }
      if (tid < 512) {
        int e4 = tid + 1024;                // 1024..1535
        float4 val = F4[e4];
        int r = e4 / 24, c4 = (e4 % 24) * 4;
        *(float4*)&Fs[r][c4] = val;
      }
      if (tid < NSC_) qv[tid] = ct[tid];
      if (tid >= 128 && tid < 192) fv[tid - 128] = ft[tid - 128];
    }

    // C prefetch (global->reg); the s_waitcnt lands in phase C, so the
    // ~900-cycle HBM latency hides under phase B's GEMM.
    float creg[3][3];
    {
      const int i0 = 3 * rw, j0 = 3 * cw;
#pragma unroll
      for (int a = 0; a < 3; ++a) {
        const float* p = Ct + (i0 + a) * NSC_ + j0;
#pragma unroll
        for (int j = 0; j < 3; ++j) creg[a][j] = p[j];
      }
    }
    __syncthreads();

    // ---- phase B: h = v + V f (tid<64);  W = V F (2x3 tiles, 1024 thr)
    if (tid < NS_) {
      float acc = vv[tid];
#pragma unroll 8
      for (int u = 0; u < NS_; ++u) acc += Vs[u][tid] * fv[u];  // V symmetric
      hv[tid] = acc;
    }
    {
      const int s0 = 2 * rw;               // 0..62
      const int j0 = 3 * cw;               // 0..93
      float acc[2][3];
#pragma unroll
      for (int a = 0; a < 2; ++a)
#pragma unroll
        for (int j = 0; j < 3; ++j) acc[a][j] = 0.f;
#pragma unroll 4
      for (int u = 0; u < NS_; ++u) {
        float av[2], bv[3];
#pragma unroll
        for (int a = 0; a < 2; ++a) av[a] = Vs[u][s0 + a];  // broadcast (V sym)
#pragma unroll
        for (int j = 0; j < 3; ++j) bv[j] = Fs[u][j0 + j];  // stride-3: conflict-free
#pragma unroll
        for (int a = 0; a < 2; ++a)
#pragma unroll
          for (int j = 0; j < 3; ++j) acc[a][j] += av[a] * bv[j];
      }
#pragma unroll
      for (int a = 0; a < 2; ++a)
#pragma unroll
        for (int j = 0; j < 3; ++j) Ws[s0 + a][j0 + j] = acc[a][j];
    }
    __syncthreads();

    // ---- phase C: Q = C + F^T W (3x3 tiles);  q += F^T h
    {
      const int i0 = 3 * rw;
      const int j0 = 3 * cw;
      float acc[3][3];
#pragma unroll
      for (int a = 0; a < 3; ++a)
#pragma unroll
        for (int j = 0; j < 3; ++j) acc[a][j] = 0.f;
#pragma unroll 4
      for (int s = 0; s < NS_; ++s) {
        float av[3], bv[3];
#pragma unroll
        for (int a = 0; a < 3; ++a) av[a] = Fs[s][i0 + a];
#pragma unroll
        for (int j = 0; j < 3; ++j) bv[j] = Ws[s][j0 + j];
#pragma unroll
        for (int a = 0; a < 3; ++a)
#pragma unroll
          for (int j = 0; j < 3; ++j) acc[a][j] += av[a] * bv[j];
      }
#pragma unroll
      for (int a = 0; a < 3; ++a)
#pragma unroll
        for (int j = 0; j < 3; ++j) Qs[i0 + a][j0 + j] = acc[a][j] + creg[a][j];
    }
    if (tid < NSC_) {
      float acc = qv[tid];
#pragma unroll 8
      for (int s = 0; s < NS_; ++s) acc += Fs[s][tid] * hv[s];
      qv[tid] = acc;
    }
    __syncthreads();

    // ---- phase D: Cholesky of Quu = L L^T (one half-wave, lanes 0..31)
    if (tid < 32) {
      const int i = tid;
      for (int j = 0; j < 32; ++j) {
        float dot = 0.f;
        for (int k = 0; k < j; ++k) dot += LT[k][i] * LT[k][j];
        float dj  = __shfl(dot, j);
        float d   = Qs[64 + j][64 + j] - dj;
        float rin = 1.0f / sqrtf(d);
        if (i == j) invd[j] = rin;
        if (i >= j) {
          float val = (i == j) ? d * rin : (Qs[64 + i][64 + j] - dot) * rin;
          LT[j][i] = val;
        }
      }
    }
    __syncthreads();

    // ---- phase E: S = Quu^{-1} [Qux | qu], one thread per RHS column (65)
    if (tid < 65) {
      float xr[32];
#pragma unroll
      for (int i = 0; i < 32; ++i) {
        float v = (tid < 64) ? Qs[64 + i][tid] : qv[64 + i];
#pragma unroll
        for (int k = 0; k < i; ++k) v -= LT[k][i] * xr[k];   // L[i][k] broadcast
        xr[i] = v * invd[i];
      }
#pragma unroll
      for (int i = 31; i >= 0; --i) {
        float v = xr[i];
#pragma unroll
        for (int k = i + 1; k < 32; ++k) v -= LT[i][k] * xr[k];  // L^T
        xr[i] = v * invd[i];
      }
      float* Sg = Sws + tb * (NC_ * 65);
#pragma unroll
      for (int i = 0; i < 32; ++i) {
        Ss[i][tid]       = xr[i];
        Sg[i * 65 + tid] = xr[i];
      }
    }
    __syncthreads();

    // ---- phase F1: Bmat = Qxu * S[:, :64] (rows {2rw,2rw+1} x cols {cw,cw+32})
    //               vn = q - Qxu S[:,64]  (tid<64)
    {
      float acc[2][2];
#pragma unroll
      for (int a = 0; a < 2; ++a)
#pragma unroll
        for (int j = 0; j < 2; ++j) acc[a][j] = 0.f;
#pragma unroll 4
      for (int m = 0; m < 32; ++m) {
        float qa[2], sb[2];
#pragma unroll
        for (int a = 0; a < 2; ++a) qa[a] = Qs[2 * rw + a][64 + m];  // broadcast
        sb[0] = Ss[m][cw];        // stride-1: conflict-free
        sb[1] = Ss[m][cw + 32];
#pragma unroll
        for (int a = 0; a < 2; ++a)
#pragma unroll
          for (int j = 0; j < 2; ++j) acc[a][j] += qa[a] * sb[j];
      }
#pragma unroll
      for (int a = 0; a < 2; ++a) {
        Bs[2 * rw + a][cw]      = acc[a][0];
        Bs[2 * rw + a][cw + 32] = acc[a][1];
      }
    }
    if (tid < NS_) {
      float acc = qv[tid];
#pragma unroll 4
      for (int m = 0; m < 32; ++m) acc -= Qs[tid][64 + m] * Ss[m][64];
      vv[tid] = acc;   // vn = qx + Qxu k  (k = -S[:,64])
    }
    __syncthreads();

    // ---- phase F2: V = sym(Qxx - Bmat)
    {
#pragma unroll
      for (int a = 0; a < 2; ++a) {
        const int i = 2 * rw + a;
        Vs[i][cw]      = Qs[i][cw]      - 0.5f * (Bs[i][cw]      + Bs[cw][i]);
        Vs[i][cw + 32] = Qs[i][cw + 32] - 0.5f * (Bs[i][cw + 32] + Bs[cw + 32][i]);
      }
    }
    __syncthreads();
  }

  // ================= forward rollout =================
  float (*FsT)[100] = Qs;   // F^T staged here (96 rows x 64 cols used)
  float* tau = qv;          // tau[0:64]=x, tau[64:96]=u
  if (tid < NS_) tau[tid] = x0g[(size_t)b * NS_ + tid];
  __syncthreads();

  for (int t = 0; t < T_; ++t) {
    const size_t tb = (size_t)t * B_ + b;
    const float* Ft = Fg + tb * (NS_ * NSC_);
    const float* ft = fg + tb * NS_;
    const float* Sg = Sws + tb * (NC_ * 65);

    for (int e = tid; e < NC_ * 65; e += 1024) Ss[e / 65][e % 65] = Sg[e];
    {
      const float4* F4 = (const float4*)Ft;
      {
        int e4 = tid;
        float4 val = F4[e4];
        int r = e4 / 24, c0 = (e4 % 24) * 4;
        FsT[c0 + 0][r] = val.x; FsT[c0 + 1][r] = val.y;
        FsT[c0 + 2][r] = val.z; FsT[c0 + 3][r] = val.w;
      }
      if (tid < 512) {
        int e4 = tid + 1024;
        float4 val = F4[e4];
        int r = e4 / 24, c0 = (e4 % 24) * 4;
        FsT[c0 + 0][r] = val.x; FsT[c0 + 1][r] = val.y;
        FsT[c0 + 2][r] = val.z; FsT[c0 + 3][r] = val.w;
      }
    }
    if (tid >= 64 && tid < 128) fv[tid - 64] = ft[tid - 64];
    __syncthreads();

    // u = K x + k = -(S[:, :64] x + S[:, 64])
    if (tid < NC_) {
      float acc = Ss[tid][64];
#pragma unroll 8
      for (int i = 0; i < NS_; ++i) acc += Ss[tid][i] * tau[i];
      tau[64 + tid] = -acc;
    }
    __syncthreads();

    // emit tau; x_next = F tau + f
    if (tid < NSC_) outg[tb * NSC_ + tid] = tau[tid];
    float xn = 0.f;
    if (tid < NS_) {
      xn = fv[tid];
#pragma unroll 8
      for (int i = 0; i < NSC_; ++i) xn += FsT[i][tid] * tau[i];
    }
    __syncthreads();
    if (tid < NS_) tau[tid] = xn;
    __syncthreads();
  }
}

extern "C" void kernel_launch(void* const* d_in, const int* in_sizes, int n_in,
                              void* d_out, int out_size, void* d_ws, size_t ws_size,
                              hipStream_t stream) {
  const float* C  = (const float*)d_in[0];
  const float* c  = (const float*)d_in[1];
  const float* F  = (const float*)d_in[2];
  const float* f  = (const float*)d_in[3];
  const float* x0 = (const float*)d_in[4];
  float* out = (float*)d_out;
  float* S   = (float*)d_ws;   // needs T*B*32*65*4 = 68.2 MB

  lqr_all<<<dim3(B_), dim3(1024), 0, stream>>>(C, c, F, f, x0, out, S);
}

// Round 4
// 5410.678 us; speedup vs baseline: 1.2654x; 1.2654x over previous
//
#include <hip/hip_runtime.h>

// Batched time-varying LQR: Riccati backward pass + forward rollout.
// T=64, B=128, NS=64, NC=32, NSC=96. One 512-thread block per batch element.
//
// Journal:
//  R1 (256 thr): 3994 us. VALUBusy 6.7%, Occ 5.8% = 1 wave/SIMD, latency-bound.
//  R3 (1024 thr): 6846 us REGRESSION. VGPR capped 64 -> spills (WRITE_SIZE
//     128MB -> 1.09GB scratch traffic). Lesson: reg budget couples to waves/SIMD.
//  R4: 512 thr, __launch_bounds__(512,2) -> 256-VGPR cap, 2 waves/SIMD, no
//     spill. Cross-timestep prefetch (C-tile/c/f in regs, F via idle waves
//     during solve). 6 barriers/step. Q symmetry for row-type LDS reads in F1.

constexpr int T_   = 64;
constexpr int B_   = 128;
constexpr int NS_  = 64;
constexpr int NC_  = 32;
constexpr int NSC_ = 96;

// LDS layout (floats), total 34464 = 137,856 B (< 160 KiB/CU, 1 block/CU)
//  Vs [64][68]  @0      Fs [64][96]  @4352    Ws [64][100] @10496
//  Qs [96][100] @16896  Ss [32][68]  @26496   LT [32][33]  @28672
//  invd[32] @29728  qv[96] @29760  hv[64] @29856  vv[64] @29920  fv[64] @29984
//  Bs [64][69]  @30048  (stride 69: breaks bank alias on Bs[j][i] col reads)

__global__ __launch_bounds__(512, 2) void lqr_all(
    const float* __restrict__ Cg, const float* __restrict__ cg,
    const float* __restrict__ Fg, const float* __restrict__ fg,
    const float* __restrict__ x0g, float* __restrict__ outg,
    float* __restrict__ Sws)
{
  const int b   = blockIdx.x;
  const int tid = threadIdx.x;

  __shared__ float smem[34464];
  float (*Vs)[68]   = (float(*)[68]) (smem + 0);
  float (*Fs)[96]   = (float(*)[96]) (smem + 4352);
  float (*Ws)[100]  = (float(*)[100])(smem + 10496);
  float (*Qs)[100]  = (float(*)[100])(smem + 16896);
  float (*Ss)[68]   = (float(*)[68]) (smem + 26496);
  float (*LT)[33]   = (float(*)[33]) (smem + 28672);
  float* invd = smem + 29728;
  float* qv   = smem + 29760;
  float* hv   = smem + 29856;
  float* vv   = smem + 29920;
  float* fv   = smem + 29984;
  float (*Bs)[69]   = (float(*)[69]) (smem + 30048);

  // init V = 0, v = 0
  for (int e = tid; e < 4352; e += 512) smem[e] = 0.f;
  if (tid < NS_) vv[tid] = 0.f;

  // ---- prologue: stage F,c,f and C-tile for t = T-1
  float creg[3][6];
  {
    const size_t tb0 = (size_t)(T_ - 1) * B_ + b;
    const float4* F4 = (const float4*)(Fg + tb0 * (NS_ * NSC_));
#pragma unroll
    for (int k = 0; k < 3; ++k) {
      int e4 = tid + k * 512;               // 0..1535
      float4 val = F4[e4];
      int r = e4 / 24, c4 = (e4 % 24) * 4;
      *(float4*)&Fs[r][c4] = val;
    }
    if (tid < NSC_) qv[tid] = cg[tb0 * NSC_ + tid];
    if (tid < NS_)  fv[tid] = fg[tb0 * NS_ + tid];
    const float* Ct = Cg + tb0 * (NSC_ * NSC_);
    const int i0 = 3 * (tid >> 4), j0 = 6 * (tid & 15);
#pragma unroll
    for (int a = 0; a < 3; ++a) {
      const float* p = Ct + (i0 + a) * NSC_ + j0;
#pragma unroll
      for (int j = 0; j < 6; ++j) creg[a][j] = p[j];
    }
  }
  __syncthreads();

  // ================= backward Riccati pass =================
  for (int t = T_ - 1; t >= 0; --t) {
    const size_t tb  = (size_t)t * B_ + b;
    const size_t tbn = tb - B_;             // t-1 (valid when t>0)

    // ---- phase B: W = V F (4x3 tiles); h = v + V f (tid<64)
    {
      const int s0 = 4 * (tid >> 5);        // 0..60
      const int j0 = 3 * (tid & 31);        // 0..93
      float acc[4][3];
#pragma unroll
      for (int a = 0; a < 4; ++a)
#pragma unroll
        for (int j = 0; j < 3; ++j) acc[a][j] = 0.f;
#pragma unroll 4
      for (int u = 0; u < NS_; ++u) {
        float av[4], bv[3];
        *(float4*)av = *(const float4*)&Vs[u][s0];   // b128, 2-way bcast
#pragma unroll
        for (int j = 0; j < 3; ++j) bv[j] = Fs[u][j0 + j];
#pragma unroll
        for (int a = 0; a < 4; ++a)
#pragma unroll
          for (int j = 0; j < 3; ++j) acc[a][j] += av[a] * bv[j];
      }
#pragma unroll
      for (int a = 0; a < 4; ++a)
#pragma unroll
        for (int j = 0; j < 3; ++j) Ws[s0 + a][j0 + j] = acc[a][j];
    }
    if (tid < NS_) {
      float acc = vv[tid];
#pragma unroll 8
      for (int u = 0; u < NS_; ++u) acc += Vs[u][tid] * fv[u];  // V symmetric
      hv[tid] = acc;
    }
    __syncthreads();

    // ---- phase C: Q = creg + F^T W (3x6 tiles); q += F^T h; issue prefetch
    float4 fN[4];
    float  ctN = 0.f, ftN = 0.f;
    if (t > 0) {                            // vmcnt lands under phase-C GEMM
      if (tid >= 128) {
        const float4* F4n = (const float4*)(Fg + tbn * (NS_ * NSC_));
#pragma unroll
        for (int k = 0; k < 4; ++k) fN[k] = F4n[(tid - 128) + k * 384];
      }
      if (tid < NSC_) ctN = cg[tbn * NSC_ + tid];
      if (tid < NS_)  ftN = fg[tbn * NS_ + tid];
    }
    {
      const int i0 = 3 * (tid >> 4);        // 0..93
      const int j0 = 6 * (tid & 15);        // 0..90
      float acc[3][6];
#pragma unroll
      for (int a = 0; a < 3; ++a)
#pragma unroll
        for (int j = 0; j < 6; ++j) acc[a][j] = 0.f;
#pragma unroll 2
      for (int s = 0; s < NS_; ++s) {
        float av[3], bv[6];
#pragma unroll
        for (int a = 0; a < 3; ++a) av[a] = Fs[s][i0 + a];
#pragma unroll
        for (int j = 0; j < 6; ++j) bv[j] = Ws[s][j0 + j];
#pragma unroll
        for (int a = 0; a < 3; ++a)
#pragma unroll
          for (int j = 0; j < 6; ++j) acc[a][j] += av[a] * bv[j];
      }
#pragma unroll
      for (int a = 0; a < 3; ++a)
#pragma unroll
        for (int j = 0; j < 6; ++j) Qs[i0 + a][j0 + j] = acc[a][j] + creg[a][j];
      if (t > 0) {                          // refill creg for t-1 (WAR on regs)
        const float* CtN = Cg + tbn * (NSC_ * NSC_);
#pragma unroll
        for (int a = 0; a < 3; ++a) {
          const float* p = CtN + (i0 + a) * NSC_ + j0;
#pragma unroll
          for (int j = 0; j < 6; ++j) creg[a][j] = p[j];
        }
      }
    }
    if (tid < NSC_) {
      float acc = qv[tid];
#pragma unroll 8
      for (int s = 0; s < NS_; ++s) acc += Fs[s][tid] * hv[s];
      qv[tid] = acc;
    }
    __syncthreads();

    // ---- phase D: Cholesky of Quu = L L^T (lanes 0..31)
    if (tid < 32) {
      const int i = tid;
      for (int j = 0; j < 32; ++j) {
        float dot = 0.f;
        for (int k = 0; k < j; ++k) dot += LT[k][i] * LT[k][j];
        float dj  = __shfl(dot, j);
        float d   = Qs[64 + j][64 + j] - dj;
        float rin = 1.0f / sqrtf(d);
        if (i == j) invd[j] = rin;
        if (i >= j) {
          float val = (i == j) ? d * rin : (Qs[64 + i][64 + j] - dot) * rin;
          LT[j][i] = val;
        }
      }
    }
    __syncthreads();

    // ---- phase E: solve (tid<65) | stage next F into Fs (tid>=128)
    if (tid < 65) {
      float xr[32];
#pragma unroll
      for (int i = 0; i < 32; ++i) {
        float v = (tid < 64) ? Qs[64 + i][tid] : qv[64 + i];
#pragma unroll
        for (int k = 0; k < i; ++k) v -= LT[k][i] * xr[k];
        xr[i] = v * invd[i];
      }
#pragma unroll
      for (int i = 31; i >= 0; --i) {
        float v = xr[i];
#pragma unroll
        for (int k = i + 1; k < 32; ++k) v -= LT[i][k] * xr[k];
        xr[i] = v * invd[i];
      }
#pragma unroll
      for (int i = 0; i < 32; ++i) Ss[i][tid] = xr[i];
    } else if (t > 0 && tid >= 128) {
#pragma unroll
      for (int k = 0; k < 4; ++k) {
        int e4 = (tid - 128) + k * 384;     // 0..1535
        int r = e4 / 24, c4 = (e4 % 24) * 4;
        *(float4*)&Fs[r][c4] = fN[k];
      }
    }
    __syncthreads();

    // ---- phase F1: Bmat = Qxu S[:, :64] (2x4, symmetric-Q row reads);
    //               vn = q - Qxu S[:,64] (tid<64)
    {
      const int r0 = 2 * (tid >> 4);        // 0..62
      const int j0 = 4 * (tid & 15);        // 0..60
      float acc[2][4];
#pragma unroll
      for (int a = 0; a < 2; ++a)
#pragma unroll
        for (int j = 0; j < 4; ++j) acc[a][j] = 0.f;
#pragma unroll 4
      for (int m = 0; m < 32; ++m) {
        float qa[2], sb[4];
        qa[0] = Qs[64 + m][r0];             // Q symmetric: row-type read
        qa[1] = Qs[64 + m][r0 + 1];
        *(float4*)sb = *(const float4*)&Ss[m][j0];
#pragma unroll
        for (int a = 0; a < 2; ++a)
#pragma unroll
          for (int j = 0; j < 4; ++j) acc[a][j] += qa[a] * sb[j];
      }
#pragma unroll
      for (int a = 0; a < 2; ++a)
#pragma unroll
        for (int j = 0; j < 4; ++j) Bs[r0 + a][j0 + j] = acc[a][j];
    }
    if (tid < NS_) {
      float acc = qv[tid];
#pragma unroll 4
      for (int m = 0; m < 32; ++m) acc -= Qs[64 + m][tid] * Ss[m][64];
      vv[tid] = acc;   // vn = qx + Qxu k  (k = -S[:,64])
    }
    __syncthreads();

    // ---- phase F2: V = sym(Qxx - B); coalesced S->global; stage next c,f
    {
      const int r0 = 2 * (tid >> 4);
      const int j0 = 4 * (tid & 15);
#pragma unroll
      for (int a = 0; a < 2; ++a)
#pragma unroll
        for (int j = 0; j < 4; ++j) {
          const int i = r0 + a, jj = j0 + j;
          Vs[i][jj] = Qs[i][jj] - 0.5f * (Bs[i][jj] + Bs[jj][i]);
        }
    }
    {
      float* Sg = Sws + tb * 2080;
#pragma unroll
      for (int k = 0; k < 5; ++k) {
        int e = tid + k * 512;
        if (e < 2080) { int i = e / 65; Sg[e] = Ss[i][e - i * 65]; }
      }
    }
    if (t > 0) {
      if (tid < NSC_) qv[tid] = ctN;
      if (tid < NS_)  fv[tid] = ftN;
    }
    __syncthreads();
  }

  // ================= forward rollout =================
  float (*FsT)[100] = Qs;   // F^T staged here (96 rows x 64 cols used)
  float* tau = qv;          // tau[0:64]=x, tau[64:96]=u
  if (tid < NS_) tau[tid] = x0g[(size_t)b * NS_ + tid];
  __syncthreads();

  for (int t = 0; t < T_; ++t) {
    const size_t tb = (size_t)t * B_ + b;
    const float* Sg = Sws + tb * 2080;

#pragma unroll
    for (int k = 0; k < 5; ++k) {
      int e = tid + k * 512;
      if (e < 2080) { int i = e / 65; Ss[i][e - i * 65] = Sg[e]; }
    }
    {
      const float4* F4 = (const float4*)(Fg + tb * (NS_ * NSC_));
#pragma unroll
      for (int k = 0; k < 3; ++k) {
        int e4 = tid + k * 512;
        float4 val = F4[e4];
        int r = e4 / 24, c0 = (e4 % 24) * 4;
        FsT[c0 + 0][r] = val.x; FsT[c0 + 1][r] = val.y;
        FsT[c0 + 2][r] = val.z; FsT[c0 + 3][r] = val.w;
      }
    }
    if (tid >= 64 && tid < 128) fv[tid - 64] = fg[tb * NS_ + (tid - 64)];
    __syncthreads();

    // u = K x + k = -(S[:, :64] x + S[:, 64])
    if (tid < NC_) {
      float acc = Ss[tid][64];
#pragma unroll 8
      for (int i = 0; i < NS_; ++i) acc += Ss[tid][i] * tau[i];
      tau[64 + tid] = -acc;
    }
    __syncthreads();

    // emit tau; x_next = F tau + f
    if (tid < NSC_) outg[tb * NSC_ + tid] = tau[tid];
    float xn = 0.f;
    if (tid < NS_) {
      xn = fv[tid];
#pragma unroll 8
      for (int i = 0; i < NSC_; ++i) xn += FsT[i][tid] * tau[i];
    }
    __syncthreads();
    if (tid < NS_) tau[tid] = xn;
    __syncthreads();
  }
}

extern "C" void kernel_launch(void* const* d_in, const int* in_sizes, int n_in,
                              void* d_out, int out_size, void* d_ws, size_t ws_size,
                              hipStream_t stream) {
  const float* C  = (const float*)d_in[0];
  const float* c  = (const float*)d_in[1];
  const float* F  = (const float*)d_in[2];
  const float* f  = (const float*)d_in[3];
  const float* x0 = (const float*)d_in[4];
  float* out = (float*)d_out;
  float* S   = (float*)d_ws;   // needs T*B*2080*4 = 68.2 MB

  lqr_all<<<dim3(B_), dim3(512), 0, stream>>>(C, c, F, f, x0, out, S);
}